// Round 1
// baseline (289.322 us; speedup 1.0000x reference)
//
#include <hip/hip_runtime.h>
#include <hip/hip_bf16.h>
#include <stdint.h>

// ---------- constants ----------
#define T_WIN   4096
#define DFULL   4096
#define DK      1024
#define NKV     2048           // concatenated K|V output columns
#define PLAYERS 8

typedef __bf16 bf16x8 __attribute__((ext_vector_type(8)));
typedef float  f32x4  __attribute__((ext_vector_type(4)));

// ---------- helpers ----------
__device__ __forceinline__ unsigned short f2bf(float f) {
    union { float f; uint32_t u; } v; v.f = f;
    uint32_t u = v.u;
    uint32_t r = (u + 0x7FFFu + ((u >> 16) & 1u)) >> 16;
    return (unsigned short)r;
}
__device__ __forceinline__ float bf2f(unsigned short u) {
    union { uint32_t u; float f; } v; v.u = ((uint32_t)u) << 16;
    return v.f;
}

// ---------- workspace layout (bytes) ----------
// x_bf16   : [4096][4096] ushort  = 33554432
// wkvT_bf16: [2048][4096] ushort  = 16777216
// kv_f32   : [4096][2048] float   = 33554432
// q,ctx,ol : 3 * 1024 float       (zeroed via memset each call)
// s,att    : 2 * 4096 float
static const size_t X_OFF   = 0;
static const size_t WT_OFF  = (size_t)T_WIN * DFULL * 2;            // 33554432
static const size_t KV_OFF  = WT_OFF + (size_t)NKV * DFULL * 2;     // 50331648
static const size_t Q_OFF   = KV_OFF + (size_t)T_WIN * NKV * 4;     // 83886080
static const size_t CTX_OFF = Q_OFF + 4096;
static const size_t OL_OFF  = CTX_OFF + 4096;
static const size_t S_OFF   = OL_OFF + 4096;
static const size_t ATT_OFF = S_OFF + (size_t)T_WIN * 4;

// =====================================================================
// K1: build x = [o_emb|d_emb gather]*16 + positional encoding, as bf16
// one block per row t, 256 threads
// =====================================================================
__global__ void build_x(const int* __restrict__ obs,
                        const float* __restrict__ o_emb,
                        const float* __restrict__ d_emb,
                        unsigned short* __restrict__ x) {
    int t = blockIdx.x;
    int tid = threadIdx.x;
    __shared__ int idx[16];   // [0..7]=o idx per player, [8..15]=d idx
    if (tid < 16) {
        int p = tid & 7;
        int which = tid >> 3;                 // 0: offense (even row), 1: defense (odd)
        int row = 2 * (t * PLAYERS + p) + which;
        const int* r = obs + (size_t)row * 9;
        int id = 0;
        #pragma unroll
        for (int j = 1; j < 9; ++j) if (r[j] == 1) id = j;
        idx[which * 8 + p] = id;
    }
    __syncthreads();
    const float LOG2_10000 = 13.287712379549449f;
    #pragma unroll
    for (int i = 0; i < 8; ++i) {
        int pc = tid + 256 * i;          // pair index 0..2047
        int c0 = pc * 2;                 // even column
        int p = c0 >> 9;                 // player
        int r = c0 & 511;
        float e0, e1;
        if (r < 256) {
            const float* e = o_emb + (size_t)idx[p] * 256;
            e0 = e[r]; e1 = e[r + 1];
        } else {
            const float* e = d_emb + (size_t)idx[8 + p] * 256;
            e0 = e[r - 256]; e1 = e[r - 255];
        }
        float freq = exp2f(-((float)c0 / (float)DFULL) * LOG2_10000);
        float ang = (float)t * freq;
        float sv, cv;
        __sincosf(ang, &sv, &cv);
        unsigned short lo = f2bf(e0 * 16.0f + sv);
        unsigned short hi = f2bf(e1 * 16.0f + cv);
        uint32_t packed = (uint32_t)lo | ((uint32_t)hi << 16);
        *(uint32_t*)(x + (size_t)t * DFULL + c0) = packed;
    }
}

// =====================================================================
// K2: transpose-cast [WK | WV] (fp32 [4096][1024] each) -> bf16 BT [2048][4096]
// 32x32 tiles, 256 threads (32x8)
// =====================================================================
__global__ void cast_wkv(const float* __restrict__ WK,
                         const float* __restrict__ WV,
                         unsigned short* __restrict__ BT) {
    __shared__ float tile[32][33];
    int kb = blockIdx.x * 32;   // k block (0..4095)
    int nb = blockIdx.y * 32;   // n block (0..2047)
    int tx = threadIdx.x & 31, ty = threadIdx.x >> 5;
    const float* W = (nb < DK) ? WK : WV;
    int ncol = (nb < DK) ? nb : nb - DK;
    #pragma unroll
    for (int i = 0; i < 32; i += 8)
        tile[ty + i][tx] = W[(size_t)(kb + ty + i) * DK + ncol + tx];
    __syncthreads();
    #pragma unroll
    for (int i = 0; i < 32; i += 8)
        BT[(size_t)(nb + ty + i) * DFULL + kb + tx] = f2bf(tile[tx][ty + i]);
}

// =====================================================================
// K3: C[M=4096][N=2048] = A[M][K=4096] * BT[N][K]^T  (bf16 in, fp32 out)
// m97 structure: 128x128 tile, BK=32, 256 thr = 4 waves (2x2 of 64x64),
// global_load_lds width 16, mfma 16x16x32 bf16
// =====================================================================
#define BM 128
#define BN 128
#define BK 32
__global__ __launch_bounds__(256) void gemm_bt(
        const unsigned short* __restrict__ A,
        const unsigned short* __restrict__ BT,
        float* __restrict__ C, int M, int N, int K) {
    __shared__ __bf16 lA[BM * BK];  // 8 KB
    __shared__ __bf16 lB[BN * BK];  // 8 KB
    int tid = threadIdx.x;
    int wave = tid >> 6, lane = tid & 63;
    int bm = blockIdx.x * BM;
    int bn = blockIdx.y * BN;
    int wm = (wave & 1) * 64;
    int wn = (wave >> 1) * 64;
    f32x4 acc[4][4] = {};

    int fm = lane & 15;
    int fk = (lane >> 4) * 8;

    for (int k0 = 0; k0 < K; k0 += BK) {
        __syncthreads();   // protect LDS from overwrite while previous iter reads
        #pragma unroll
        for (int call = 0; call < 2; ++call) {
            int chunk = call * 256 + tid;      // 0..511, 16B each
            int row = chunk >> 2;              // 0..127
            int kc = chunk & 3;                // 0..3 (8 bf16 each)
            const unsigned short* ga = A + (size_t)(bm + row) * K + k0 + kc * 8;
            const unsigned short* gb = BT + (size_t)(bn + row) * K + k0 + kc * 8;
            int ldsbase = (call * 256 + wave * 64) * 8;  // elements; wave-uniform
            __builtin_amdgcn_global_load_lds(
                (const __attribute__((address_space(1))) void*)ga,
                (__attribute__((address_space(3))) void*)(lA + ldsbase), 16, 0, 0);
            __builtin_amdgcn_global_load_lds(
                (const __attribute__((address_space(1))) void*)gb,
                (__attribute__((address_space(3))) void*)(lB + ldsbase), 16, 0, 0);
        }
        __syncthreads();   // compiler emits vmcnt(0) drain before barrier

        bf16x8 af[4], bfr[4];
        #pragma unroll
        for (int i = 0; i < 4; ++i)
            af[i] = *(const bf16x8*)(lA + (wm + i * 16 + fm) * BK + fk);
        #pragma unroll
        for (int j = 0; j < 4; ++j)
            bfr[j] = *(const bf16x8*)(lB + (wn + j * 16 + fm) * BK + fk);
        #pragma unroll
        for (int i = 0; i < 4; ++i)
            #pragma unroll
            for (int j = 0; j < 4; ++j)
                acc[i][j] = __builtin_amdgcn_mfma_f32_16x16x32_bf16(
                    af[i], bfr[j], acc[i][j], 0, 0, 0);
    }

    // epilogue: D[m = quad*4+reg][n = lane&15]
    int cn = lane & 15;
    int cm = (lane >> 4) * 4;
    #pragma unroll
    for (int i = 0; i < 4; ++i)
        #pragma unroll
        for (int j = 0; j < 4; ++j) {
            int m = bm + wm + i * 16 + cm;
            int n = bn + wn + j * 16 + cn;
            #pragma unroll
            for (int r = 0; r < 4; ++r)
                C[(size_t)(m + r) * N + n] = acc[i][j][r];
        }
}

// =====================================================================
// K4: q_last[n] = sum_k x[4095][k] * WQ[k][n]   (fp32, partial per k-chunk)
// grid 64: kc = bid>>2 (16 chunks of 256), nc = bid&3 (4 chunks of 256)
// =====================================================================
__global__ void qlast_k(const unsigned short* __restrict__ x,
                        const float* __restrict__ WQ,
                        float* __restrict__ q) {
    int kc = blockIdx.x >> 2, nc = blockIdx.x & 3;
    int n = nc * 256 + threadIdx.x;
    const unsigned short* xr = x + (size_t)(T_WIN - 1) * DFULL + kc * 256;
    const float* Wc = WQ + (size_t)kc * 256 * DK + n;
    float s = 0.0f;
    for (int k = 0; k < 256; ++k)
        s += bf2f(xr[k]) * Wc[(size_t)k * DK];
    atomicAdd(&q[n], s);
}

// =====================================================================
// K5: scores[t] = dot(q, kv[t][0:1024]) / 32  — one wave per t
// =====================================================================
__global__ void scores_k(const float* __restrict__ kv,
                         const float* __restrict__ q,
                         float* __restrict__ s) {
    int wave = threadIdx.x >> 6, lane = threadIdx.x & 63;
    int t = blockIdx.x * 4 + wave;
    const float* kr = kv + (size_t)t * NKV;
    float acc = 0.0f;
    #pragma unroll
    for (int j = lane; j < DK; j += 64) acc += kr[j] * q[j];
    #pragma unroll
    for (int off = 32; off; off >>= 1) acc += __shfl_down(acc, off, 64);
    if (lane == 0) s[t] = acc * (1.0f / 32.0f);
}

// =====================================================================
// K6: softmax over 4096 scores — single block of 1024 threads
// =====================================================================
__global__ void softmax_k(const float* __restrict__ s, float* __restrict__ att) {
    __shared__ float redm[16], reds[16];
    int tid = threadIdx.x;
    float v0 = s[tid], v1 = s[tid + 1024], v2 = s[tid + 2048], v3 = s[tid + 3072];
    float m = fmaxf(fmaxf(v0, v1), fmaxf(v2, v3));
    #pragma unroll
    for (int off = 32; off; off >>= 1) m = fmaxf(m, __shfl_down(m, off, 64));
    if ((tid & 63) == 0) redm[tid >> 6] = m;
    __syncthreads();
    if (tid == 0) {
        float mm = redm[0];
        for (int i = 1; i < 16; ++i) mm = fmaxf(mm, redm[i]);
        redm[0] = mm;
    }
    __syncthreads();
    m = redm[0];
    float e0 = expf(v0 - m), e1 = expf(v1 - m), e2 = expf(v2 - m), e3 = expf(v3 - m);
    float sum = e0 + e1 + e2 + e3;
    #pragma unroll
    for (int off = 32; off; off >>= 1) sum += __shfl_down(sum, off, 64);
    if ((tid & 63) == 0) reds[tid >> 6] = sum;
    __syncthreads();
    if (tid == 0) {
        float ss = 0.0f;
        for (int i = 0; i < 16; ++i) ss += reds[i];
        reds[0] = ss;
    }
    __syncthreads();
    float inv = 1.0f / reds[0];
    att[tid] = e0 * inv; att[tid + 1024] = e1 * inv;
    att[tid + 2048] = e2 * inv; att[tid + 3072] = e3 * inv;
}

// =====================================================================
// K7: ctx[j] = sum_t att[t] * v[t][j], v = kv[:, 1024:]
// grid 64: tc = bid>>2 (16 chunks of 256 t), jc = bid&3
// =====================================================================
__global__ void ctx_k(const float* __restrict__ kv,
                      const float* __restrict__ att,
                      float* __restrict__ ctx) {
    int tc = blockIdx.x >> 2, jc = blockIdx.x & 3;
    int j = jc * 256 + threadIdx.x;
    const float* vp = kv + (size_t)tc * 256 * NKV + DK + j;
    const float* ap = att + tc * 256;
    float s = 0.0f;
    for (int t = 0; t < 256; ++t)
        s += ap[t] * vp[(size_t)t * NKV];
    atomicAdd(&ctx[j], s);
}

// =====================================================================
// K8: o_last[m] = sum_j ctx[j] * WO[j][m]
// grid 16: jc = bid>>2 (4 chunks of 256 j), mc = bid&3
// =====================================================================
__global__ void olast_k(const float* __restrict__ ctx,
                        const float* __restrict__ WO,
                        float* __restrict__ ol) {
    int jc = blockIdx.x >> 2, mc = blockIdx.x & 3;
    int m = mc * 256 + threadIdx.x;
    const float* cp = ctx + jc * 256;
    const float* Wp = WO + (size_t)jc * 256 * DK + m;
    float s = 0.0f;
    for (int j = 0; j < 256; ++j)
        s += cp[j] * Wp[(size_t)j * DK];
    atomicAdd(&ol[m], s);
}

// =====================================================================
// K9: heads — out[0:64]=h@Wo_pol.T+bo, out[64:128]=h@Wd_pol.T+bd, out[128]=h@Wv.T+bv
// h = relu(o_last). One block (256 thr) per output.
// =====================================================================
__global__ void heads_k(const float* __restrict__ ol,
                        const float* __restrict__ Wo_pol, const float* __restrict__ bo_pol,
                        const float* __restrict__ Wd_pol, const float* __restrict__ bd_pol,
                        const float* __restrict__ Wv,     const float* __restrict__ bv,
                        float* __restrict__ out) {
    __shared__ float red[4];
    int o = blockIdx.x;
    const float* W; float b;
    if (o < 64)       { W = Wo_pol + (size_t)o * DK;        b = bo_pol[o]; }
    else if (o < 128) { W = Wd_pol + (size_t)(o - 64) * DK; b = bd_pol[o - 64]; }
    else              { W = Wv;                              b = bv[0]; }
    float s = 0.0f;
    for (int m = threadIdx.x; m < DK; m += 256)
        s += fmaxf(ol[m], 0.0f) * W[m];
    #pragma unroll
    for (int off = 32; off; off >>= 1) s += __shfl_down(s, off, 64);
    int wave = threadIdx.x >> 6, lane = threadIdx.x & 63;
    if (lane == 0) red[wave] = s;
    __syncthreads();
    if (threadIdx.x == 0) out[o] = red[0] + red[1] + red[2] + red[3] + b;
}

// =====================================================================
extern "C" void kernel_launch(void* const* d_in, const int* in_sizes, int n_in,
                              void* d_out, int out_size, void* d_ws, size_t ws_size,
                              hipStream_t stream) {
    const int*   obs    = (const int*)  d_in[0];
    const float* o_emb  = (const float*)d_in[1];
    const float* d_emb  = (const float*)d_in[2];
    const float* WQ     = (const float*)d_in[3];
    const float* WK     = (const float*)d_in[4];
    const float* WV     = (const float*)d_in[5];
    const float* WO     = (const float*)d_in[6];
    const float* Wo_pol = (const float*)d_in[7];
    const float* bo_pol = (const float*)d_in[8];
    const float* Wd_pol = (const float*)d_in[9];
    const float* bd_pol = (const float*)d_in[10];
    const float* Wv     = (const float*)d_in[11];
    const float* bv     = (const float*)d_in[12];
    float* out = (float*)d_out;

    char* ws = (char*)d_ws;
    unsigned short* xbf = (unsigned short*)(ws + X_OFF);
    unsigned short* wt  = (unsigned short*)(ws + WT_OFF);
    float* kv  = (float*)(ws + KV_OFF);
    float* q   = (float*)(ws + Q_OFF);
    float* ctx = (float*)(ws + CTX_OFF);
    float* ol  = (float*)(ws + OL_OFF);
    float* s   = (float*)(ws + S_OFF);
    float* att = (float*)(ws + ATT_OFF);

    build_x<<<T_WIN, 256, 0, stream>>>(obs, o_emb, d_emb, xbf);
    cast_wkv<<<dim3(DFULL / 32, NKV / 32), 256, 0, stream>>>(WK, WV, wt);
    gemm_bt<<<dim3(T_WIN / BM, NKV / BN), 256, 0, stream>>>(xbf, wt, kv, T_WIN, NKV, DFULL);
    hipMemsetAsync(ws + Q_OFF, 0, 3 * 4096, stream);   // zero q, ctx, ol
    qlast_k<<<64, 256, 0, stream>>>(xbf, WQ, q);
    scores_k<<<T_WIN / 4, 256, 0, stream>>>(kv, q, s);
    softmax_k<<<1, 1024, 0, stream>>>(s, att);
    ctx_k<<<64, 256, 0, stream>>>(kv, att, ctx);
    olast_k<<<16, 256, 0, stream>>>(ctx, WO, ol);
    heads_k<<<129, 256, 0, stream>>>(ol, Wo_pol, bo_pol, Wd_pol, bd_pol, Wv, bv, out);
}

// Round 2
// 169.229 us; speedup vs baseline: 1.7096x; 1.7096x over previous
//
#include <hip/hip_runtime.h>
#include <hip/hip_bf16.h>
#include <stdint.h>

// ---------- constants ----------
#define T_WIN   4096
#define DFULL   4096
#define DK      1024
#define PLAYERS 8

// ---------- helpers ----------
__device__ __forceinline__ unsigned short f2bf(float f) {
    union { float f; uint32_t u; } v; v.f = f;
    uint32_t u = v.u;
    uint32_t r = (u + 0x7FFFu + ((u >> 16) & 1u)) >> 16;
    return (unsigned short)r;
}
__device__ __forceinline__ float bf2f(unsigned short u) {
    union { uint32_t u; float f; } v; v.u = ((uint32_t)u) << 16;
    return v.f;
}

// ---------- workspace layout (bytes) ----------
// x_bf16 : [4096][4096] ushort = 33554432
// xlast  : [4096] float  (fp32 copy of last row, better accuracy for q)
// kq,s,att : [4096] float each
// q, ax(4096), ctx, ol : zeroed block (atomicAdd targets)
static const size_t X_OFF   = 0;
static const size_t XL_OFF  = (size_t)T_WIN * DFULL * 2;   // 33554432
static const size_t KQ_OFF  = XL_OFF  + 16384;
static const size_t S_OFF   = KQ_OFF  + 16384;
static const size_t ATT_OFF = S_OFF   + 16384;
static const size_t Q_OFF   = ATT_OFF + 16384;             // ---- zero from here
static const size_t AX_OFF  = Q_OFF   + 4096;
static const size_t CTX_OFF = AX_OFF  + 16384;
static const size_t OL_OFF  = CTX_OFF + 4096;
static const size_t ZERO_BYTES = 4096 + 16384 + 4096 + 4096;  // q+ax+ctx+ol = 28672

// =====================================================================
// K1: build x = [o_emb|d_emb gather]*sqrt(256) + positional encoding, bf16.
// Also writes fp32 last row. One block per row t, 256 threads.
// =====================================================================
__global__ void build_x(const int* __restrict__ obs,
                        const float* __restrict__ o_emb,
                        const float* __restrict__ d_emb,
                        unsigned short* __restrict__ x,
                        float* __restrict__ xlast) {
    int t = blockIdx.x;
    int tid = threadIdx.x;
    __shared__ int idx[16];   // [0..7]=offense idx per player, [8..15]=defense
    if (tid < 16) {
        int p = tid & 7;
        int which = tid >> 3;
        int row = 2 * (t * PLAYERS + p) + which;
        const int* r = obs + (size_t)row * 9;
        int id = 0;
        #pragma unroll
        for (int j = 1; j < 9; ++j) if (r[j] == 1) id = j;
        idx[which * 8 + p] = id;
    }
    __syncthreads();
    const float LOG2_10000 = 13.287712379549449f;
    bool last = (t == T_WIN - 1);
    #pragma unroll
    for (int i = 0; i < 8; ++i) {
        int pc = tid + 256 * i;          // pair index 0..2047
        int c0 = pc * 2;
        int p = c0 >> 9;                 // player
        int r = c0 & 511;
        float e0, e1;
        if (r < 256) {
            const float* e = o_emb + (size_t)idx[p] * 256;
            e0 = e[r]; e1 = e[r + 1];
        } else {
            const float* e = d_emb + (size_t)idx[8 + p] * 256;
            e0 = e[r - 256]; e1 = e[r - 255];
        }
        float freq = exp2f(-((float)c0 / (float)DFULL) * LOG2_10000);
        float ang = (float)t * freq;
        float sv, cv;
        __sincosf(ang, &sv, &cv);
        float f0 = e0 * 16.0f + sv;
        float f1 = e1 * 16.0f + cv;
        uint32_t packed = (uint32_t)f2bf(f0) | ((uint32_t)f2bf(f1) << 16);
        *(uint32_t*)(x + (size_t)t * DFULL + c0) = packed;
        if (last) { xlast[c0] = f0; xlast[c0 + 1] = f1; }
    }
}

// =====================================================================
// K2: q[n] = sum_k xlast[k] * WQ[k][n]  (fp32). grid 128 = 32 kchunks x 4 nchunks
// =====================================================================
__global__ void qlast_k(const float* __restrict__ xlast,
                        const float* __restrict__ WQ,
                        float* __restrict__ q) {
    int kc = blockIdx.x >> 2, nc = blockIdx.x & 3;   // kc: 0..31 (128 k each)
    int n = nc * 256 + threadIdx.x;
    const float* xr = xlast + kc * 128;
    const float* Wc = WQ + (size_t)kc * 128 * DK + n;
    float s = 0.0f;
    for (int k = 0; k < 128; ++k)
        s += xr[k] * Wc[(size_t)k * DK];
    atomicAdd(&q[n], s);
}

// =====================================================================
// K3: kq[c] = (sum_n WK[c][n] * q[n]) / 32   — one wave per row c
// =====================================================================
__global__ void kq_k(const float* __restrict__ WK,
                     const float* __restrict__ q,
                     float* __restrict__ kq) {
    int wave = threadIdx.x >> 6, lane = threadIdx.x & 63;
    int c = blockIdx.x * 4 + wave;
    const float4* wr = (const float4*)(WK + (size_t)c * DK);
    const float4* q4 = (const float4*)q;
    float acc = 0.0f;
    #pragma unroll
    for (int i = 0; i < 4; ++i) {
        float4 w = wr[i * 64 + lane];
        float4 qq = q4[i * 64 + lane];
        acc += w.x * qq.x + w.y * qq.y + w.z * qq.z + w.w * qq.w;
    }
    #pragma unroll
    for (int off = 32; off; off >>= 1) acc += __shfl_down(acc, off, 64);
    if (lane == 0) kq[c] = acc * (1.0f / 32.0f);
}

// =====================================================================
// K4: s[t] = x[t] . kq   — one wave per row t, kq staged in LDS
// =====================================================================
__global__ void scores_k(const unsigned short* __restrict__ x,
                         const float* __restrict__ kq,
                         float* __restrict__ s) {
    __shared__ float lkq[DFULL];
    int tid = threadIdx.x;
    #pragma unroll
    for (int i = 0; i < 4; ++i)
        ((float4*)lkq)[tid + i * 256] = ((const float4*)kq)[tid + i * 256];
    __syncthreads();
    int wave = tid >> 6, lane = tid & 63;
    int t = blockIdx.x * 4 + wave;
    const unsigned short* xr = x + (size_t)t * DFULL;
    float acc = 0.0f;
    #pragma unroll
    for (int i = 0; i < 8; ++i) {
        int base = i * 512 + lane * 8;
        uint4 w = *(const uint4*)(xr + base);
        acc += bf2f((unsigned short)(w.x & 0xFFFF)) * lkq[base + 0];
        acc += bf2f((unsigned short)(w.x >> 16))    * lkq[base + 1];
        acc += bf2f((unsigned short)(w.y & 0xFFFF)) * lkq[base + 2];
        acc += bf2f((unsigned short)(w.y >> 16))    * lkq[base + 3];
        acc += bf2f((unsigned short)(w.z & 0xFFFF)) * lkq[base + 4];
        acc += bf2f((unsigned short)(w.z >> 16))    * lkq[base + 5];
        acc += bf2f((unsigned short)(w.w & 0xFFFF)) * lkq[base + 6];
        acc += bf2f((unsigned short)(w.w >> 16))    * lkq[base + 7];
    }
    #pragma unroll
    for (int off = 32; off; off >>= 1) acc += __shfl_down(acc, off, 64);
    if (lane == 0) s[t] = acc;
}

// =====================================================================
// K5: softmax over 4096 scores — single block of 1024 threads
// =====================================================================
__global__ void softmax_k(const float* __restrict__ s, float* __restrict__ att) {
    __shared__ float redm[16], reds[16];
    int tid = threadIdx.x;
    float v0 = s[tid], v1 = s[tid + 1024], v2 = s[tid + 2048], v3 = s[tid + 3072];
    float m = fmaxf(fmaxf(v0, v1), fmaxf(v2, v3));
    #pragma unroll
    for (int off = 32; off; off >>= 1) m = fmaxf(m, __shfl_down(m, off, 64));
    if ((tid & 63) == 0) redm[tid >> 6] = m;
    __syncthreads();
    if (tid == 0) {
        float mm = redm[0];
        for (int i = 1; i < 16; ++i) mm = fmaxf(mm, redm[i]);
        redm[0] = mm;
    }
    __syncthreads();
    m = redm[0];
    float e0 = expf(v0 - m), e1 = expf(v1 - m), e2 = expf(v2 - m), e3 = expf(v3 - m);
    float sum = e0 + e1 + e2 + e3;
    #pragma unroll
    for (int off = 32; off; off >>= 1) sum += __shfl_down(sum, off, 64);
    if ((tid & 63) == 0) reds[tid >> 6] = sum;
    __syncthreads();
    if (tid == 0) {
        float ss = 0.0f;
        for (int i = 0; i < 16; ++i) ss += reds[i];
        reds[0] = ss;
    }
    __syncthreads();
    float inv = 1.0f / reds[0];
    att[tid] = e0 * inv; att[tid + 1024] = e1 * inv;
    att[tid + 2048] = e2 * inv; att[tid + 3072] = e3 * inv;
}

// =====================================================================
// K6: ax[c] = sum_t att[t] * x[t][c]
// grid (8 colchunks of 512, 32 tchunks of 128); thread handles 2 cols
// =====================================================================
__global__ void ax_k(const unsigned short* __restrict__ x,
                     const float* __restrict__ att,
                     float* __restrict__ ax) {
    int c0 = blockIdx.x * 512 + threadIdx.x * 2;
    int t0 = blockIdx.y * 128;
    float acc0 = 0.0f, acc1 = 0.0f;
    const unsigned short* xp = x + (size_t)t0 * DFULL + c0;
    for (int r = 0; r < 128; ++r) {
        float a = att[t0 + r];
        uint32_t w = *(const uint32_t*)(xp + (size_t)r * DFULL);
        acc0 += a * bf2f((unsigned short)(w & 0xFFFF));
        acc1 += a * bf2f((unsigned short)(w >> 16));
    }
    atomicAdd(&ax[c0], acc0);
    atomicAdd(&ax[c0 + 1], acc1);
}

// =====================================================================
// K7: ctx[n] = sum_c ax[c] * WV[c][n]   grid 128 = 32 cchunks x 4 nchunks
// =====================================================================
__global__ void ctxv_k(const float* __restrict__ ax,
                       const float* __restrict__ WV,
                       float* __restrict__ ctx) {
    int cc = blockIdx.x >> 2, nc = blockIdx.x & 3;
    int n = nc * 256 + threadIdx.x;
    const float* ap = ax + cc * 128;
    const float* Wp = WV + (size_t)cc * 128 * DK + n;
    float s = 0.0f;
    for (int c = 0; c < 128; ++c)
        s += ap[c] * Wp[(size_t)c * DK];
    atomicAdd(&ctx[n], s);
}

// =====================================================================
// K8: ol[m] = sum_j ctx[j] * WO[j][m]   grid 64 = 16 jchunks x 4 mchunks
// =====================================================================
__global__ void olast_k(const float* __restrict__ ctx,
                        const float* __restrict__ WO,
                        float* __restrict__ ol) {
    int jc = blockIdx.x >> 2, mc = blockIdx.x & 3;
    int m = mc * 256 + threadIdx.x;
    const float* cp = ctx + jc * 64;
    const float* Wp = WO + (size_t)jc * 64 * DK + m;
    float s = 0.0f;
    for (int j = 0; j < 64; ++j)
        s += cp[j] * Wp[(size_t)j * DK];
    atomicAdd(&ol[m], s);
}

// =====================================================================
// K9: heads — out[0:64]=h@Wo_pol.T+bo, out[64:128]=h@Wd_pol.T+bd, out[128]=h@Wv.T+bv
// =====================================================================
__global__ void heads_k(const float* __restrict__ ol,
                        const float* __restrict__ Wo_pol, const float* __restrict__ bo_pol,
                        const float* __restrict__ Wd_pol, const float* __restrict__ bd_pol,
                        const float* __restrict__ Wv,     const float* __restrict__ bv,
                        float* __restrict__ out) {
    __shared__ float red[4];
    int o = blockIdx.x;
    const float* W; float b;
    if (o < 64)       { W = Wo_pol + (size_t)o * DK;        b = bo_pol[o]; }
    else if (o < 128) { W = Wd_pol + (size_t)(o - 64) * DK; b = bd_pol[o - 64]; }
    else              { W = Wv;                              b = bv[0]; }
    float s = 0.0f;
    for (int m = threadIdx.x; m < DK; m += 256)
        s += fmaxf(ol[m], 0.0f) * W[m];
    #pragma unroll
    for (int off = 32; off; off >>= 1) s += __shfl_down(s, off, 64);
    int wave = threadIdx.x >> 6, lane = threadIdx.x & 63;
    if (lane == 0) red[wave] = s;
    __syncthreads();
    if (threadIdx.x == 0) out[o] = red[0] + red[1] + red[2] + red[3] + b;
}

// =====================================================================
extern "C" void kernel_launch(void* const* d_in, const int* in_sizes, int n_in,
                              void* d_out, int out_size, void* d_ws, size_t ws_size,
                              hipStream_t stream) {
    const int*   obs    = (const int*)  d_in[0];
    const float* o_emb  = (const float*)d_in[1];
    const float* d_emb  = (const float*)d_in[2];
    const float* WQ     = (const float*)d_in[3];
    const float* WK     = (const float*)d_in[4];
    const float* WV     = (const float*)d_in[5];
    const float* WO     = (const float*)d_in[6];
    const float* Wo_pol = (const float*)d_in[7];
    const float* bo_pol = (const float*)d_in[8];
    const float* Wd_pol = (const float*)d_in[9];
    const float* bd_pol = (const float*)d_in[10];
    const float* Wv     = (const float*)d_in[11];
    const float* bv     = (const float*)d_in[12];
    float* out = (float*)d_out;

    char* ws = (char*)d_ws;
    unsigned short* xbf = (unsigned short*)(ws + X_OFF);
    float* xlast = (float*)(ws + XL_OFF);
    float* kq    = (float*)(ws + KQ_OFF);
    float* s     = (float*)(ws + S_OFF);
    float* att   = (float*)(ws + ATT_OFF);
    float* q     = (float*)(ws + Q_OFF);
    float* ax    = (float*)(ws + AX_OFF);
    float* ctx   = (float*)(ws + CTX_OFF);
    float* ol    = (float*)(ws + OL_OFF);

    hipMemsetAsync(ws + Q_OFF, 0, ZERO_BYTES, stream);   // q, ax, ctx, ol

    build_x<<<T_WIN, 256, 0, stream>>>(obs, o_emb, d_emb, xbf, xlast);
    qlast_k<<<128, 256, 0, stream>>>(xlast, WQ, q);
    kq_k<<<DFULL / 4, 256, 0, stream>>>(WK, q, kq);
    scores_k<<<T_WIN / 4, 256, 0, stream>>>(xbf, kq, s);
    softmax_k<<<1, 1024, 0, stream>>>(s, att);
    ax_k<<<dim3(8, 32), 256, 0, stream>>>(xbf, att, ax);
    ctxv_k<<<128, 256, 0, stream>>>(ax, WV, ctx);
    olast_k<<<64, 256, 0, stream>>>(ctx, WO, ol);
    heads_k<<<129, 256, 0, stream>>>(ol, Wo_pol, bo_pol, Wd_pol, bd_pol, Wv, bv, out);
}

// Round 4
// 164.094 us; speedup vs baseline: 1.7631x; 1.0313x over previous
//
#include <hip/hip_runtime.h>
#include <stdint.h>

// ---------- constants ----------
#define T_WIN   4096
#define DFULL   4096
#define DK      1024

// ---------- workspace layout (bytes), non-overlapping ----------
static const size_t IDX_OFF  = 0;         // idxb [4096][16] uchar   = 65536
static const size_t XL_OFF   = 65536;     // xlast [4096] f          = 16384
static const size_t FRQ_OFF  = 81920;     // freqt [2048] f          = 8192
static const size_t KQ_OFF   = 90112;     // kq    [4096] f          = 16384
static const size_t S_OFF    = 106496;    // s     [4096] f          = 16384
static const size_t ATT_OFF  = 122880;    // att   [4096] f          = 16384
// ---- zeroed region (atomic targets), 41984 B = 2624 float4 ----
static const size_t QP_OFF   = 139264;    // q partials [4][1024] f  = 16384
static const size_t AXPE_OFF = 155648;    // axpe [4096] f           = 16384
static const size_t W_OFF    = 172032;    // weight [144] f (pad 1K) = 1024
static const size_t CTX_OFF  = 173056;    // ctx [1024] f            = 4096
static const size_t OL_OFF   = 177152;    // ol  [1024] f            = 4096
// zero region end = 181248; ZERO_BYTES = 181248 - 139264 = 41984

#define LOG2_10000 13.287712379549449f

// =====================================================================
// K1: blocks 0..255: idx extraction (one-hot argmax) -> idxb[t][16]
//     block 256: xlast[c] = emb*16 + pe(4095,c)  (fp32)
//     block 257: zero atomic targets + freq table
// =====================================================================
__global__ void idx_k(const int* __restrict__ obs,
                      const float* __restrict__ o_emb,
                      const float* __restrict__ d_emb,
                      unsigned char* __restrict__ idxb,
                      float* __restrict__ xlast,
                      float* __restrict__ freqt,
                      float* __restrict__ zbase) {
    int b = blockIdx.x, tid = threadIdx.x;
    if (b < 256) {
        int g = b * 256 + tid;               // obs row 0..65535 = t*16 + p*2 + which
        const int* r = obs + (size_t)g * 9;
        int id = 0;
        #pragma unroll
        for (int j = 1; j < 9; ++j) id += j * r[j];
        int t = g >> 4;
        int p = (g >> 1) & 7, which = g & 1;
        idxb[t * 16 + which * 8 + p] = (unsigned char)id;
    } else if (b == 256) {
        __shared__ int lidx[16];
        if (tid < 16) {
            int row = 65520 + tid;           // rows of t = 4095
            const int* r = obs + (size_t)row * 9;
            int id = 0;
            #pragma unroll
            for (int j = 1; j < 9; ++j) id += j * r[j];
            int p = tid >> 1, which = tid & 1;
            lidx[which * 8 + p] = id;
        }
        __syncthreads();
        #pragma unroll
        for (int i = 0; i < 16; ++i) {
            int c = tid + 256 * i;
            int p = c >> 9, rr = c & 511;
            int seg, r; const float* tab;
            if (rr < 256) { seg = p;     r = rr;       tab = o_emb; }
            else          { seg = 8 + p; r = rr - 256; tab = d_emb; }
            float e = tab[lidx[seg] * 256 + r];
            float f = exp2f(-((float)(c & ~1) * (1.0f / 4096.0f)) * LOG2_10000);
            float sv, cv;
            __sincosf(4095.0f * f, &sv, &cv);
            xlast[c] = e * 16.0f + ((c & 1) ? cv : sv);
        }
    } else {
        float4 z4 = {0.f, 0.f, 0.f, 0.f};
        float4* z = (float4*)zbase;
        for (int i = tid; i < 2624; i += 256) z[i] = z4;
        for (int i = tid; i < 2048; i += 256)
            freqt[i] = exp2f(-((float)(2 * i) * (1.0f / 4096.0f)) * LOG2_10000);
    }
}

// =====================================================================
// K2: q partials: qp[sc][n] += sum_{k in 16-row block} xlast[k]*WQ[k][n]
// grid 256 blocks; sc = blockIdx >> 6 (4 separate partials to cut atomics)
// =====================================================================
__global__ void q_k(const float* __restrict__ xlast,
                    const float* __restrict__ WQ,
                    float* __restrict__ qp) {
    int kc = blockIdx.x, tid = threadIdx.x;
    const float4* W4 = (const float4*)WQ;
    float4 acc = {0.f, 0.f, 0.f, 0.f};
    int kb = kc * 16;
    #pragma unroll
    for (int k = 0; k < 16; ++k) {
        float xv = xlast[kb + k];
        float4 w = W4[(size_t)(kb + k) * 256 + tid];
        acc.x += xv * w.x; acc.y += xv * w.y;
        acc.z += xv * w.z; acc.w += xv * w.w;
    }
    float* dst = qp + (kc >> 6) * 1024 + tid * 4;
    atomicAdd(dst + 0, acc.x);
    atomicAdd(dst + 1, acc.y);
    atomicAdd(dst + 2, acc.z);
    atomicAdd(dst + 3, acc.w);
}

// =====================================================================
// K3: kq[c] = (sum_n WK[c][n]*q[n]) / 32 ; q = sum of 4 partials
// grid 1024 blocks, one wave per row
// =====================================================================
__global__ void kq_k(const float* __restrict__ WK,
                     const float* __restrict__ qp,
                     float* __restrict__ kq) {
    __shared__ float4 qls[256];
    int tid = threadIdx.x;
    const float4* p4 = (const float4*)qp;
    float4 a = p4[tid], b = p4[256 + tid], c = p4[512 + tid], d = p4[768 + tid];
    qls[tid] = {a.x + b.x + c.x + d.x, a.y + b.y + c.y + d.y,
                a.z + b.z + c.z + d.z, a.w + b.w + c.w + d.w};
    __syncthreads();
    int wave = tid >> 6, lane = tid & 63;
    int cc = blockIdx.x * 4 + wave;
    const float4* W4 = (const float4*)(WK + (size_t)cc * DK);
    float acc = 0.0f;
    #pragma unroll
    for (int i = 0; i < 4; ++i) {
        float4 w = W4[i * 64 + lane];
        float4 q = qls[i * 64 + lane];
        acc += w.x * q.x + w.y * q.y + w.z * q.z + w.w * q.w;
    }
    #pragma unroll
    for (int off = 32; off; off >>= 1) acc += __shfl_down(acc, off, 64);
    if (lane == 0) kq[cc] = acc * (1.0f / 32.0f);
}

// =====================================================================
// K4: s[t] = sum_seg Dot[seg][idx[t,seg]] + pedot[t]
// grid 256 blocks x 16 t each. Dot recomputed per block (LDS-hot, cheap).
// =====================================================================
__global__ __launch_bounds__(256) void scores_k(
        const float* __restrict__ kq,
        const float* __restrict__ o_emb, const float* __restrict__ d_emb,
        const float* __restrict__ freqt,
        const unsigned char* __restrict__ idxb,
        float* __restrict__ s) {
    __shared__ float lkq[4096];
    __shared__ float lemb[18 * 257];   // padded rows
    __shared__ float lfrq[2048];
    __shared__ float ldot[144];
    __shared__ float lped[256];
    int tid = threadIdx.x, blk = blockIdx.x;
    for (int i = tid; i < 1024; i += 256)
        ((float4*)lkq)[i] = ((const float4*)kq)[i];
    for (int i = tid; i < 512; i += 256)
        ((float4*)lfrq)[i] = ((const float4*)freqt)[i];
    for (int i = tid; i < 4608; i += 256) {
        int row = i >> 8, r = i & 255;
        lemb[row * 257 + r] = (row < 9) ? o_emb[row * 256 + r]
                                        : d_emb[(row - 9) * 256 + r];
    }
    __syncthreads();
    // Dot[seg][id] = 16 * dot256(emb_id, kq segment)
    if (tid < 144) {
        int seg = tid / 9, id = tid % 9;
        int base = (seg < 8) ? seg * 512 : (seg - 8) * 512 + 256;
        const float* e = lemb + ((seg < 8) ? id : (9 + id)) * 257;
        float a = 0.0f;
        for (int rr = 0; rr < 256; ++rr) {
            int r = (rr + seg * 4) & 255;   // stagger across segs
            a += e[r] * lkq[base + r];
        }
        ldot[tid] = 16.0f * a;
    }
    // pedot: 16 threads per t, 128 freq-pairs each
    int tt = tid >> 4, sub = tid & 15;
    int t = blk * 16 + tt;
    float acc = 0.0f;
    for (int jj = 0; jj < 128; ++jj) {
        int j = sub * 128 + ((jj + 2 * sub) & 127);   // bank stagger
        float f = lfrq[j];
        float sv, cv;
        __sincosf((float)t * f, &sv, &cv);
        acc += sv * lkq[2 * j] + cv * lkq[2 * j + 1];
    }
    lped[tt * 16 + sub] = acc;
    __syncthreads();
    if (tid < 16) {
        int t2 = blk * 16 + tid;
        float tot = 0.0f;
        #pragma unroll
        for (int i = 0; i < 16; ++i) tot += lped[tid * 16 + i];
        const uint32_t* ip = (const uint32_t*)(idxb + t2 * 16);
        uint32_t u0 = ip[0], u1 = ip[1], u2 = ip[2], u3 = ip[3];
        #pragma unroll
        for (int seg = 0; seg < 16; ++seg) {
            uint32_t u = (seg < 4) ? u0 : (seg < 8) ? u1 : (seg < 12) ? u2 : u3;
            int id = (u >> ((seg & 3) * 8)) & 0xFF;
            tot += ldot[seg * 9 + id];
        }
        s[t2] = tot;
    }
}

// =====================================================================
// K5: softmax over 4096 scores — single block of 1024 threads
// =====================================================================
__global__ void softmax_k(const float* __restrict__ s, float* __restrict__ att) {
    __shared__ float redm[16], reds[16];
    int tid = threadIdx.x;
    float v0 = s[tid], v1 = s[tid + 1024], v2 = s[tid + 2048], v3 = s[tid + 3072];
    float m = fmaxf(fmaxf(v0, v1), fmaxf(v2, v3));
    #pragma unroll
    for (int off = 32; off; off >>= 1) m = fmaxf(m, __shfl_down(m, off, 64));
    if ((tid & 63) == 0) redm[tid >> 6] = m;
    __syncthreads();
    if (tid == 0) {
        float mm = redm[0];
        for (int i = 1; i < 16; ++i) mm = fmaxf(mm, redm[i]);
        redm[0] = mm;
    }
    __syncthreads();
    m = redm[0];
    float e0 = expf(v0 - m), e1 = expf(v1 - m), e2 = expf(v2 - m), e3 = expf(v3 - m);
    float sum = e0 + e1 + e2 + e3;
    #pragma unroll
    for (int off = 32; off; off >>= 1) sum += __shfl_down(sum, off, 64);
    if ((tid & 63) == 0) reds[tid >> 6] = sum;
    __syncthreads();
    if (tid == 0) {
        float ss = 0.0f;
        for (int i = 0; i < 16; ++i) ss += reds[i];
        reds[0] = ss;
    }
    __syncthreads();
    float inv = 1.0f / reds[0];
    att[tid] = e0 * inv; att[tid + 1024] = e1 * inv;
    att[tid + 2048] = e2 * inv; att[tid + 3072] = e3 * inv;
}

// =====================================================================
// K6: weight[seg][id] = sum_t att[t]·[idx[t,seg]==id]  (LDS hist)
//     axpe[c] = sum_t att[t]*pe[t][c]  (anchored rotation recurrence)
// grid 128 blocks x 256 thr
// =====================================================================
__global__ void att_post_k(const float* __restrict__ att,
                           const float* __restrict__ freqt,
                           const unsigned char* __restrict__ idxb,
                           float* __restrict__ weight,
                           float* __restrict__ axpe) {
    __shared__ float lh[144];
    int tid = threadIdx.x, b = blockIdx.x;
    if (tid < 144) lh[tid] = 0.0f;
    __syncthreads();
    #pragma unroll
    for (int i = 0; i < 2; ++i) {
        int it = tid + 256 * i;
        int t = b * 32 + (it >> 4), seg = it & 15;
        int id = idxb[t * 16 + seg];
        atomicAdd(&lh[seg * 9 + id], att[t]);
    }
    __syncthreads();
    if (tid < 144) atomicAdd(&weight[tid], lh[tid]);
    // axpe: thread = (freq pair j, t-chunk of 256); re-anchor every 64 steps
    int g = b * 256 + tid;
    int j = g & 2047;
    int t0 = (g >> 11) * 256;
    float f = freqt[j];
    float sf, cf;
    __sincosf(f, &sf, &cf);
    float ss = 0.0f, sc = 0.0f;
    float sv = 0.f, cv = 0.f;
    for (int i = 0; i < 256; ++i) {
        if ((i & 63) == 0) __sincosf((float)(t0 + i) * f, &sv, &cv);
        float a = att[t0 + i];
        ss += a * sv; sc += a * cv;
        float ns = sv * cf + cv * sf;
        cv = cv * cf - sv * sf;
        sv = ns;
    }
    atomicAdd(&axpe[2 * j], ss);
    atomicAdd(&axpe[2 * j + 1], sc);
}

// =====================================================================
// K7: ctx[n] = sum_c ax[c]*WV[c][n];  ax built on the fly per c-chunk:
//     ax[c] = axpe[c] + 16 * sum_id weight[seg][id]*emb[id][r]
// grid (cc 32 x nc 4) = 128 blocks
// =====================================================================
__global__ void ctxv_k(const float* __restrict__ weight,
                       const float* __restrict__ axpe,
                       const float* __restrict__ o_emb,
                       const float* __restrict__ d_emb,
                       const float* __restrict__ WV,
                       float* __restrict__ ctx) {
    __shared__ float lax[128];
    int tid = threadIdx.x;
    int cc = blockIdx.x >> 2, nc = blockIdx.x & 3;
    if (tid < 128) {
        int c = cc * 128 + tid;
        int p = c >> 9, rr = c & 511;
        int seg, r; const float* tab;
        if (rr < 256) { seg = p;     r = rr;       tab = o_emb; }
        else          { seg = 8 + p; r = rr - 256; tab = d_emb; }
        float a = 0.0f;
        #pragma unroll
        for (int id = 0; id < 9; ++id)
            a += weight[seg * 9 + id] * tab[id * 256 + r];
        lax[tid] = axpe[c] + 16.0f * a;
    }
    __syncthreads();
    int n = nc * 256 + tid;
    const float* Wp = WV + (size_t)cc * 128 * DK + n;
    float acc = 0.0f;
    for (int i = 0; i < 128; ++i)
        acc += lax[i] * Wp[(size_t)i * DK];
    atomicAdd(&ctx[n], acc);
}

// =====================================================================
// K8: ol[m] = sum_j ctx[j]*WO[j][m]   grid (jc 16 x mc 4) = 64 blocks
// =====================================================================
__global__ void olast_k(const float* __restrict__ ctx,
                        const float* __restrict__ WO,
                        float* __restrict__ ol) {
    __shared__ float lc[64];
    int tid = threadIdx.x;
    int jc = blockIdx.x >> 2, mc = blockIdx.x & 3;
    if (tid < 64) lc[tid] = ctx[jc * 64 + tid];
    __syncthreads();
    int m = mc * 256 + tid;
    const float* Wp = WO + (size_t)jc * 64 * DK + m;
    float acc = 0.0f;
    for (int j = 0; j < 64; ++j)
        acc += lc[j] * Wp[(size_t)j * DK];
    atomicAdd(&ol[m], acc);
}

// =====================================================================
// K9: heads
// =====================================================================
__global__ void heads_k(const float* __restrict__ ol,
                        const float* __restrict__ Wo_pol, const float* __restrict__ bo_pol,
                        const float* __restrict__ Wd_pol, const float* __restrict__ bd_pol,
                        const float* __restrict__ Wv,     const float* __restrict__ bv,
                        float* __restrict__ out) {
    __shared__ float red[4];
    int o = blockIdx.x;
    const float* W; float b;
    if (o < 64)       { W = Wo_pol + (size_t)o * DK;        b = bo_pol[o]; }
    else if (o < 128) { W = Wd_pol + (size_t)(o - 64) * DK; b = bd_pol[o - 64]; }
    else              { W = Wv;                              b = bv[0]; }
    float s = 0.0f;
    for (int m = threadIdx.x; m < DK; m += 256)
        s += fmaxf(ol[m], 0.0f) * W[m];
    #pragma unroll
    for (int off = 32; off; off >>= 1) s += __shfl_down(s, off, 64);
    int wave = threadIdx.x >> 6, lane = threadIdx.x & 63;
    if (lane == 0) red[wave] = s;
    __syncthreads();
    if (threadIdx.x == 0) out[o] = red[0] + red[1] + red[2] + red[3] + b;
}

// =====================================================================
extern "C" void kernel_launch(void* const* d_in, const int* in_sizes, int n_in,
                              void* d_out, int out_size, void* d_ws, size_t ws_size,
                              hipStream_t stream) {
    const int*   obs    = (const int*)  d_in[0];
    const float* o_emb  = (const float*)d_in[1];
    const float* d_emb  = (const float*)d_in[2];
    const float* WQ     = (const float*)d_in[3];
    const float* WK     = (const float*)d_in[4];
    const float* WV     = (const float*)d_in[5];
    const float* WO     = (const float*)d_in[6];
    const float* Wo_pol = (const float*)d_in[7];
    const float* bo_pol = (const float*)d_in[8];
    const float* Wd_pol = (const float*)d_in[9];
    const float* bd_pol = (const float*)d_in[10];
    const float* Wv     = (const float*)d_in[11];
    const float* bv     = (const float*)d_in[12];
    float* out = (float*)d_out;

    char* ws = (char*)d_ws;
    unsigned char* idxb = (unsigned char*)(ws + IDX_OFF);
    float* xlast = (float*)(ws + XL_OFF);
    float* freqt = (float*)(ws + FRQ_OFF);
    float* kq    = (float*)(ws + KQ_OFF);
    float* s     = (float*)(ws + S_OFF);
    float* att   = (float*)(ws + ATT_OFF);
    float* qp    = (float*)(ws + QP_OFF);
    float* axpe  = (float*)(ws + AXPE_OFF);
    float* wgt   = (float*)(ws + W_OFF);
    float* ctx   = (float*)(ws + CTX_OFF);
    float* ol    = (float*)(ws + OL_OFF);

    idx_k<<<258, 256, 0, stream>>>(obs, o_emb, d_emb, idxb, xlast, freqt, qp);
    q_k<<<256, 256, 0, stream>>>(xlast, WQ, qp);
    kq_k<<<1024, 256, 0, stream>>>(WK, qp, kq);
    scores_k<<<256, 256, 0, stream>>>(kq, o_emb, d_emb, freqt, idxb, s);
    softmax_k<<<1, 1024, 0, stream>>>(s, att);
    att_post_k<<<128, 256, 0, stream>>>(att, freqt, idxb, wgt, axpe);
    ctxv_k<<<128, 256, 0, stream>>>(wgt, axpe, o_emb, d_emb, WV, ctx);
    olast_k<<<64, 256, 0, stream>>>(ctx, WO, ol);
    heads_k<<<129, 256, 0, stream>>>(ol, Wo_pol, bo_pol, Wd_pol, bd_pol, Wv, bv, out);
}